// Round 10
// baseline (273.592 us; speedup 1.0000x reference)
//
#include <hip/hip_runtime.h>
#include <hip/hip_bf16.h>
#include <cmath>
#include <stdint.h>

#define B_ 2
#define S_ 2048
#define D_ 2048
#define H_ 16
#define HKV_ 2
#define DH_ 128
#define G_ 8
#define DKV_ 256   // HKV*DH
#define NQKV_ 2560 // D_ + 2*DKV

typedef _Float16 f16;
typedef _Float16 f16x8 __attribute__((ext_vector_type(8)));
typedef _Float16 f16x4 __attribute__((ext_vector_type(4)));
typedef float f32x4 __attribute__((ext_vector_type(4)));

__device__ __forceinline__ void gload_lds16(const void* g, void* lds) {
  __builtin_amdgcn_global_load_lds((const __attribute__((address_space(1))) void*)g,
                                   (__attribute__((address_space(3))) void*)lds,
                                   16, 0, 0);
}

__global__ void cast_kernel(const float* __restrict__ in, f16* __restrict__ out, int n4) {
  int i = blockIdx.x * blockDim.x + threadIdx.x;
  int stride = gridDim.x * blockDim.x;
  for (; i < n4; i += stride) {
    float4 v = reinterpret_cast<const float4*>(in)[i];
    f16x4 o = { (f16)v.x, (f16)v.y, (f16)v.z, (f16)v.w };
    reinterpret_cast<f16x4*>(out)[i] = o;
  }
}

// C[m][n] = sum_k A[m][k]*Bm[n][k] + bias[n].  1-D grid (nwg % 8 == 0), XCD-swizzled.
// Double-buffered LDS, stage(t+1) overlaps compute(t).
// EPI 0: float row-major to oF (width N).
// EPI 1: fused QKV routing: col<2048 -> oQ row-major 2048; col<2304 -> oK row-major 256;
//        else -> oV kv-interleaved: V[s][d] at oV[(s>>2)*1024 + d*4 + (s&3)], d=col-2304.
template<int EPI>
__global__ __launch_bounds__(256)
void gemm_core(const f16* __restrict__ A, const f16* __restrict__ Bm,
               const float* __restrict__ bias,
               f16* __restrict__ oQ, f16* __restrict__ oK, f16* __restrict__ oV,
               float* __restrict__ oF,
               int M, int N, int K, int nbx) {
  __shared__ __align__(16) f16 sA[2][128 * 64];
  __shared__ __align__(16) f16 sB[2][128 * 64];
  const int tid  = threadIdx.x;
  const int lane = tid & 63;
  const int w    = tid >> 6;
  const int wr   = w >> 1, wc = w & 1;
  const int r16  = lane & 15, grp = lane >> 4;
  const int nwg  = gridDim.x;
  const int cpx  = nwg >> 3;
  const int lg   = (blockIdx.x & 7) * cpx + (blockIdx.x >> 3);  // bijective XCD swizzle
  const int bm   = (lg / nbx) * 128;
  const int bn   = (lg % nbx) * 128;

  f32x4 acc[4][4] = {};

  auto stage = [&](int k0, int buf) {   // 8 gload_lds per thread
#pragma unroll
    for (int j = 0; j < 4; ++j) {
      int seg = j * 4 + w;
      int e = seg * 512 + lane * 8;
      int r = e >> 6, c = e & 63;
      gload_lds16(A  + (size_t)(bm + r) * K + k0 + c, &sA[buf][seg * 512]);
      gload_lds16(Bm + (size_t)(bn + r) * K + k0 + c, &sB[buf][seg * 512]);
    }
  };

  stage(0, 0);
  asm volatile("s_waitcnt vmcnt(0)" ::: "memory");
  __builtin_amdgcn_s_barrier();

  const int nk = K >> 6;
  for (int t = 0; t < nk; ++t) {
    const int buf = t & 1;
    if (t + 1 < nk) stage((t + 1) << 6, buf ^ 1);

#pragma unroll
    for (int kk = 0; kk < 64; kk += 32) {
      f16x8 af[4], bf[4];
#pragma unroll
      for (int m = 0; m < 4; ++m)
        af[m] = *reinterpret_cast<const f16x8*>(&sA[buf][(wr * 64 + m * 16 + r16) * 64 + kk + grp * 8]);
#pragma unroll
      for (int n = 0; n < 4; ++n)
        bf[n] = *reinterpret_cast<const f16x8*>(&sB[buf][(wc * 64 + n * 16 + r16) * 64 + kk + grp * 8]);
      __builtin_amdgcn_s_setprio(1);
#pragma unroll
      for (int m = 0; m < 4; ++m)
#pragma unroll
        for (int n = 0; n < 4; ++n)
          acc[m][n] = __builtin_amdgcn_mfma_f32_16x16x32_f16(af[m], bf[n], acc[m][n], 0, 0, 0);
      __builtin_amdgcn_s_setprio(0);
    }

    asm volatile("s_waitcnt vmcnt(0)" ::: "memory");  // next tile landed (overlapped compute)
    __builtin_amdgcn_s_barrier();
  }

#pragma unroll
  for (int n = 0; n < 4; ++n) {
    int col = bn + wc * 64 + n * 16 + r16;
    float bv = bias ? bias[col] : 0.f;
#pragma unroll
    for (int m = 0; m < 4; ++m) {
      int row0 = bm + wr * 64 + m * 16 + grp * 4;   // 4-aligned
      if constexpr (EPI == 0) {
#pragma unroll
        for (int j = 0; j < 4; ++j)
          oF[(size_t)(row0 + j) * N + col] = acc[m][n][j] + bv;
      } else {
        if (bn < 2048) {
#pragma unroll
          for (int j = 0; j < 4; ++j)
            oQ[(size_t)(row0 + j) * 2048 + col] = (f16)(acc[m][n][j] + bv);
        } else if (bn < 2304) {
#pragma unroll
          for (int j = 0; j < 4; ++j)
            oK[(size_t)(row0 + j) * 256 + (col - 2048)] = (f16)(acc[m][n][j] + bv);
        } else {
          f16x4 st;
#pragma unroll
          for (int j = 0; j < 4; ++j) st[j] = (f16)(acc[m][n][j] + bv);
          *reinterpret_cast<f16x4*>(&oV[(size_t)(row0 >> 2) * 1024 + (col - 2304) * 4]) = st;
        }
      }
    }
  }
}

// Flash attention, causal, GQA.  1024 blocks, one task each.
// Balanced schedule: combo = bid&7 (= XCD -> L2-locality for (b,kvh)),
// v = (bid>>3)&31, u = bid>>8; qt = {2v, 2v+1, 126-2v, 127-2v}[u].
// Every CU's 4 blocks total exactly 130 kv-32 iterations.
// Block = 4 waves = 4 q-heads sharing one kv-head's K/V LDS tiles.
// 2-buffer LDS (32KB), depth-1 prefetch, lane-local defer-max vote, setprio MFMA.
__global__ __launch_bounds__(256)
void attn_kernel(const f16* __restrict__ Q, const f16* __restrict__ K,
                 const f16* __restrict__ V4, f16* __restrict__ O) {
  __shared__ __align__(16) f16 sK[2][4096];
  __shared__ __align__(16) f16 sV[2][4096];

  const int tid  = threadIdx.x;
  const int lane = tid & 63;
  const int w    = tid >> 6;
  const int qi   = lane & 15, grp = lane >> 4;
  const int bid  = blockIdx.x;
  const int combo = bid & 7;
  const int v    = (bid >> 3) & 31;
  const int u    = bid >> 8;
  const int qt   = (u == 0) ? 2 * v : (u == 1) ? 2 * v + 1 : (u == 2) ? 126 - 2 * v : 127 - 2 * v;
  const int hh   = combo & 1;
  const int kvh  = (combo >> 1) & 1;
  const int b    = (combo >> 2) & 1;
  const int hq   = kvh * 8 + hh * 4 + w;
  const f16 SCL2 = (f16)(0.08838834764831845f * 1.44269504088896f);  // 1/sqrt(128)*log2(e)

  const f16* Kb = K  + (size_t)b * S_ * DKV_ + kvh * DH_;
  const f16* Vb = V4 + (size_t)b * S_ * DKV_ + kvh * 512;

  auto stage = [&](int t32, int buf) {   // exactly 4 vm loads per thread
#pragma unroll
    for (int p2 = 0; p2 < 2; ++p2) {
      int ci = p2 * 256 + tid;
      int r = ci >> 4, cs = ci & 15;
      gload_lds16(Kb + (size_t)(t32 * 32 + r) * DKV_ + ((cs ^ (r & 7)) * 8),
                  (char*)&sK[buf][0] + p2 * 4096 + w * 1024);
      int g = ci >> 6, cc = ci & 63;
      gload_lds16(Vb + (size_t)(t32 * 8 + g) * 1024 + ((cc ^ g) * 8),
                  (char*)&sV[buf][0] + p2 * 4096 + w * 1024);
    }
  };

  const int n32 = (qt >> 1) + 1;
  const int q_pos = qt * 16 + qi;

  const size_t qbase = ((size_t)(b * S_ + qt * 16 + qi)) * D_ + hq * DH_;
  f16x8 qf[4];
#pragma unroll
  for (int kd = 0; kd < 4; ++kd) {
    qf[kd] = *reinterpret_cast<const f16x8*>(Q + qbase + kd * 32 + grp * 8);
#pragma unroll
    for (int e = 0; e < 8; ++e) qf[kd][e] *= SCL2;
  }

  float m = -INFINITY, lsum = 0.f;
  f32x4 accO[8] = {};

  stage(0, 0);
  asm volatile("s_waitcnt vmcnt(0)" ::: "memory");
  __builtin_amdgcn_s_barrier();

  for (int t = 0; t < n32; ++t) {
    const int buf = t & 1;
    if (t + 1 < n32) stage(t + 1, buf ^ 1);   // overlaps this iter's compute

    const int kv0 = t * 32;
    const f16* sKb = &sK[buf][0];
    const f16* sVb = &sV[buf][0];

    // QK^T (swapped): s{0,1}[jj] = S^T[kv0+half*16+grp*4+jj][q=qi], log2 units
    f32x4 s0 = {}, s1 = {};
#pragma unroll
    for (int kd = 0; kd < 4; ++kd) {
      const int cx = ((kd * 4 + grp) ^ (qi & 7)) << 3;
      f16x8 k0 = *reinterpret_cast<const f16x8*>(sKb + qi * 128 + cx);
      f16x8 k1 = *reinterpret_cast<const f16x8*>(sKb + (16 + qi) * 128 + cx);
      __builtin_amdgcn_s_setprio(1);
      s0 = __builtin_amdgcn_mfma_f32_16x16x32_f16(k0, qf[kd], s0, 0, 0, 0);
      s1 = __builtin_amdgcn_mfma_f32_16x16x32_f16(k1, qf[kd], s1, 0, 0, 0);
      __builtin_amdgcn_s_setprio(0);
    }
    float p[8];
#pragma unroll
    for (int jj = 0; jj < 4; ++jj) { p[jj] = s0[jj]; p[4 + jj] = s1[jj]; }
    if (t == n32 - 1) {              // only the last tile can cross the diagonal
#pragma unroll
      for (int jj = 0; jj < 4; ++jj) {
        int kvp = kv0 + grp * 4 + jj;
        p[jj]     = (kvp > q_pos)      ? -INFINITY : p[jj];
        p[4 + jj] = (kvp + 16 > q_pos) ? -INFINITY : p[4 + jj];
      }
    }
    float tm = -INFINITY;
#pragma unroll
    for (int i = 0; i < 8; ++i) tm = fmaxf(tm, p[i]);
    if (!__all(tm <= m + 8.f)) {     // defer-max: rescale only on real growth (rare)
      float r = tm;
      r = fmaxf(r, __shfl_xor(r, 16));
      r = fmaxf(r, __shfl_xor(r, 32));
      float mn = fmaxf(m, r);
      float sc = exp2f(m - mn);
      m = mn;
      lsum *= sc;
#pragma unroll
      for (int dt = 0; dt < 8; ++dt)
#pragma unroll
        for (int jj = 0; jj < 4; ++jj) accO[dt][jj] *= sc;
    }
    float ps = 0.f;
#pragma unroll
    for (int i = 0; i < 8; ++i) {
      p[i] = exp2f(p[i] - m);
      ps += p[i];
    }
    lsum += ps;                      // per-lane partial, reduced at end

    f16x4 pf0 = { (f16)p[0], (f16)p[1], (f16)p[2], (f16)p[3] };
    f16x4 pf1 = { (f16)p[4], (f16)p[5], (f16)p[6], (f16)p[7] };
#pragma unroll
    for (int dt = 0; dt < 8; ++dt) {
      const int dl = dt * 16 + qi;
      const int c  = dl >> 1;
      f16x4 v0 = *reinterpret_cast<const f16x4*>(
          sVb + grp * 512 + ((c ^ grp) << 3) + (dl & 1) * 4);
      f16x4 v1 = *reinterpret_cast<const f16x4*>(
          sVb + (grp + 4) * 512 + ((c ^ (grp + 4)) << 3) + (dl & 1) * 4);
      __builtin_amdgcn_s_setprio(1);
      accO[dt] = __builtin_amdgcn_mfma_f32_16x16x16f16(v0, pf0, accO[dt], 0, 0, 0);
      accO[dt] = __builtin_amdgcn_mfma_f32_16x16x16f16(v1, pf1, accO[dt], 0, 0, 0);
      __builtin_amdgcn_s_setprio(0);
    }

    asm volatile("s_waitcnt vmcnt(0)" ::: "memory");  // next tile landed
    __builtin_amdgcn_s_barrier();
  }

  lsum += __shfl_xor(lsum, 16);
  lsum += __shfl_xor(lsum, 32);
  float inv_l = 1.f / lsum;
  const size_t obase = ((size_t)(b * S_ + qt * 16 + qi)) * D_ + hq * DH_;
#pragma unroll
  for (int dt = 0; dt < 8; ++dt) {
    f16x4 st;
#pragma unroll
    for (int jj = 0; jj < 4; ++jj) st[jj] = (f16)(accO[dt][jj] * inv_l);
    *reinterpret_cast<f16x4*>(&O[obase + dt * 16 + grp * 4]) = st;
  }
}

extern "C" void kernel_launch(void* const* d_in, const int* in_sizes, int n_in,
                              void* d_out, int out_size, void* d_ws, size_t ws_size,
                              hipStream_t stream) {
  const float* x  = (const float*)d_in[0];
  const float* Wq = (const float*)d_in[1];
  const float* bq = (const float*)d_in[2];
  const float* Wk = (const float*)d_in[3];
  const float* bk = (const float*)d_in[4];
  const float* Wv = (const float*)d_in[5];
  const float* bv = (const float*)d_in[6];
  const float* Wo = (const float*)d_in[7];
  const float* bo = (const float*)d_in[8];
  float* out = (float*)d_out;

  char* ws = (char*)d_ws;
  size_t off = 0;
  auto alloc = [&](size_t bytes) {
    char* p = ws + off;
    off += (bytes + 255) & ~(size_t)255;
    return p;
  };
  f16*   xh    = (f16*)alloc((size_t)B_ * S_ * D_ * 2);
  f16*   wqkv  = (f16*)alloc((size_t)NQKV_ * D_ * 2);
  f16*   woh   = (f16*)alloc((size_t)D_ * D_ * 2);
  f16*   qh    = (f16*)alloc((size_t)B_ * S_ * D_ * 2);
  f16*   kh    = (f16*)alloc((size_t)B_ * S_ * DKV_ * 2);
  f16*   v4h   = (f16*)alloc((size_t)B_ * S_ * DKV_ * 2);
  f16*   ah    = (f16*)alloc((size_t)B_ * S_ * D_ * 2);
  float* bqkv  = (float*)alloc((size_t)NQKV_ * 4);

  auto cast = [&](const float* in, f16* o, int n) {
    int n4 = n / 4;
    int grid = (n4 + 255) / 256;
    if (grid > 2048) grid = 2048;
    cast_kernel<<<dim3(grid), dim3(256), 0, stream>>>(in, o, n4);
  };
  cast(x,  xh, B_ * S_ * D_);
  cast(Wq, wqkv,                               D_ * D_);
  cast(Wk, wqkv + (size_t)D_ * D_,             DKV_ * D_);
  cast(Wv, wqkv + (size_t)(D_ + DKV_) * D_,    DKV_ * D_);
  cast(Wo, woh, D_ * D_);
  (void)hipMemcpyAsync(bqkv,             bq, D_ * 4,   hipMemcpyDeviceToDevice, stream);
  (void)hipMemcpyAsync(bqkv + D_,        bk, DKV_ * 4, hipMemcpyDeviceToDevice, stream);
  (void)hipMemcpyAsync(bqkv + D_ + DKV_, bv, DKV_ * 4, hipMemcpyDeviceToDevice, stream);

  const int M = B_ * S_;
  gemm_core<1><<<dim3((M / 128) * (NQKV_ / 128)), 256, 0, stream>>>(
      xh, wqkv, bqkv, qh, kh, v4h, nullptr, M, NQKV_, D_, NQKV_ / 128);

  attn_kernel<<<dim3(1024), 256, 0, stream>>>(qh, kh, v4h, ah);

  gemm_core<0><<<dim3((M / 128) * (D_ / 128)), 256, 0, stream>>>(
      ah, woh, bo, nullptr, nullptr, nullptr, out, M, D_, D_, D_ / 128);
}

// Round 11
// 238.562 us; speedup vs baseline: 1.1468x; 1.1468x over previous
//
#include <hip/hip_runtime.h>
#include <hip/hip_bf16.h>
#include <cmath>
#include <stdint.h>

#define B_ 2
#define S_ 2048
#define D_ 2048
#define H_ 16
#define HKV_ 2
#define DH_ 128
#define G_ 8
#define DKV_ 256   // HKV*DH
#define NQKV_ 2560 // D_ + 2*DKV

typedef _Float16 f16;
typedef _Float16 f16x8 __attribute__((ext_vector_type(8)));
typedef _Float16 f16x4 __attribute__((ext_vector_type(4)));
typedef float f32x4 __attribute__((ext_vector_type(4)));

__device__ __forceinline__ void gload_lds16(const void* g, void* lds) {
  __builtin_amdgcn_global_load_lds((const __attribute__((address_space(1))) void*)g,
                                   (__attribute__((address_space(3))) void*)lds,
                                   16, 0, 0);
}

__global__ void cast_kernel(const float* __restrict__ in, f16* __restrict__ out, int n4) {
  int i = blockIdx.x * blockDim.x + threadIdx.x;
  int stride = gridDim.x * blockDim.x;
  for (; i < n4; i += stride) {
    float4 v = reinterpret_cast<const float4*>(in)[i];
    f16x4 o = { (f16)v.x, (f16)v.y, (f16)v.z, (f16)v.w };
    reinterpret_cast<f16x4*>(out)[i] = o;
  }
}

// C[m][n] = sum_k A[m][k]*Bm[n][k] + bias[n].  1-D grid (nwg % 8 == 0), XCD-swizzled.
// Double-buffered LDS, stage(t+1) overlaps compute(t).   (r7-exact, no setprio)
template<int EPI>
__global__ __launch_bounds__(256)
void gemm_core(const f16* __restrict__ A, const f16* __restrict__ Bm,
               const float* __restrict__ bias,
               f16* __restrict__ oQ, f16* __restrict__ oK, f16* __restrict__ oV,
               float* __restrict__ oF,
               int M, int N, int K, int nbx) {
  __shared__ __align__(16) f16 sA[2][128 * 64];
  __shared__ __align__(16) f16 sB[2][128 * 64];
  const int tid  = threadIdx.x;
  const int lane = tid & 63;
  const int w    = tid >> 6;
  const int wr   = w >> 1, wc = w & 1;
  const int r16  = lane & 15, grp = lane >> 4;
  const int nwg  = gridDim.x;
  const int cpx  = nwg >> 3;
  const int lg   = (blockIdx.x & 7) * cpx + (blockIdx.x >> 3);  // bijective XCD swizzle
  const int bm   = (lg / nbx) * 128;
  const int bn   = (lg % nbx) * 128;

  f32x4 acc[4][4] = {};

  auto stage = [&](int k0, int buf) {   // 8 gload_lds per thread
#pragma unroll
    for (int j = 0; j < 4; ++j) {
      int seg = j * 4 + w;
      int e = seg * 512 + lane * 8;
      int r = e >> 6, c = e & 63;
      gload_lds16(A  + (size_t)(bm + r) * K + k0 + c, &sA[buf][seg * 512]);
      gload_lds16(Bm + (size_t)(bn + r) * K + k0 + c, &sB[buf][seg * 512]);
    }
  };

  stage(0, 0);
  asm volatile("s_waitcnt vmcnt(0)" ::: "memory");
  __builtin_amdgcn_s_barrier();

  const int nk = K >> 6;
  for (int t = 0; t < nk; ++t) {
    const int buf = t & 1;
    if (t + 1 < nk) stage((t + 1) << 6, buf ^ 1);

#pragma unroll
    for (int kk = 0; kk < 64; kk += 32) {
      f16x8 af[4], bf[4];
#pragma unroll
      for (int m = 0; m < 4; ++m)
        af[m] = *reinterpret_cast<const f16x8*>(&sA[buf][(wr * 64 + m * 16 + r16) * 64 + kk + grp * 8]);
#pragma unroll
      for (int n = 0; n < 4; ++n)
        bf[n] = *reinterpret_cast<const f16x8*>(&sB[buf][(wc * 64 + n * 16 + r16) * 64 + kk + grp * 8]);
#pragma unroll
      for (int m = 0; m < 4; ++m)
#pragma unroll
        for (int n = 0; n < 4; ++n)
          acc[m][n] = __builtin_amdgcn_mfma_f32_16x16x32_f16(af[m], bf[n], acc[m][n], 0, 0, 0);
    }

    asm volatile("s_waitcnt vmcnt(0)" ::: "memory");  // next tile landed (overlapped compute)
    __builtin_amdgcn_s_barrier();
  }

#pragma unroll
  for (int n = 0; n < 4; ++n) {
    int col = bn + wc * 64 + n * 16 + r16;
    float bv = bias ? bias[col] : 0.f;
#pragma unroll
    for (int m = 0; m < 4; ++m) {
      int row0 = bm + wr * 64 + m * 16 + grp * 4;   // 4-aligned
      if constexpr (EPI == 0) {
#pragma unroll
        for (int j = 0; j < 4; ++j)
          oF[(size_t)(row0 + j) * N + col] = acc[m][n][j] + bv;
      } else {
        if (bn < 2048) {
#pragma unroll
          for (int j = 0; j < 4; ++j)
            oQ[(size_t)(row0 + j) * 2048 + col] = (f16)(acc[m][n][j] + bv);
        } else if (bn < 2304) {
#pragma unroll
          for (int j = 0; j < 4; ++j)
            oK[(size_t)(row0 + j) * 256 + (col - 2048)] = (f16)(acc[m][n][j] + bv);
        } else {
          f16x4 st;
#pragma unroll
          for (int j = 0; j < 4; ++j) st[j] = (f16)(acc[m][n][j] + bv);
          *reinterpret_cast<f16x4*>(&oV[(size_t)(row0 >> 2) * 1024 + (col - 2304) * 4]) = st;
        }
      }
    }
  }
}

// Flash attention, causal, GQA.  1024 blocks, one task each:
//   (b,kvh,hh) = bid&7, qt = 127 - (bid>>3)  (longest-first dynamic-LPT dispatch).
// Block = 4 waves = 4 q-heads sharing one kv-head's K/V LDS tiles.
// KVBLK=64: 2-buffer LDS (64KB total), depth-1 prefetch, two 32-kv halves per tile.
__global__ __launch_bounds__(256)
void attn_kernel(const f16* __restrict__ Q, const f16* __restrict__ K,
                 const f16* __restrict__ V4, f16* __restrict__ O) {
  __shared__ __align__(16) f16 sK[2][8192];   // [buf][64 rows x 128], XOR-swizzled 16B chunks
  __shared__ __align__(16) f16 sV[2][8192];   // [buf][16 grp x 512],  XOR-swizzled 16B chunks

  const int tid  = threadIdx.x;
  const int lane = tid & 63;
  const int w    = tid >> 6;
  const int qi   = lane & 15, grp = lane >> 4;
  const int bid  = blockIdx.x;
  const int hh   = bid & 1;
  const int kvh  = (bid >> 1) & 1;
  const int b    = (bid >> 2) & 1;
  const int qt   = 127 - (bid >> 3);   // longest tasks dispatch first
  const int hq   = kvh * 8 + hh * 4 + w;
  const f16 SCL2 = (f16)(0.08838834764831845f * 1.44269504088896f);  // 1/sqrt(128)*log2(e)

  const f16* Kb = K  + (size_t)b * S_ * DKV_ + kvh * DH_;
  const f16* Vb = V4 + (size_t)b * S_ * DKV_ + kvh * 512;

  auto stage = [&](int t64, int buf) {   // exactly 8 vm loads per thread (64 kv rows)
#pragma unroll
    for (int p4 = 0; p4 < 4; ++p4) {
      int ci = p4 * 256 + tid;
      int r = ci >> 4, cs = ci & 15;
      gload_lds16(Kb + (size_t)(t64 * 64 + r) * DKV_ + ((cs ^ (r & 7)) * 8),
                  (char*)&sK[buf][0] + p4 * 4096 + w * 1024);
      int g = ci >> 6, cc = ci & 63;
      gload_lds16(Vb + (size_t)(t64 * 16 + g) * 1024 + ((cc ^ g) * 8),
                  (char*)&sV[buf][0] + p4 * 4096 + w * 1024);
    }
  };

  const int nt    = (qt >> 2) + 1;     // 64-kv tiles
  const int q_pos = qt * 16 + qi;
  const int q_hi  = qt * 16 + 15;

  const size_t qbase = ((size_t)(b * S_ + qt * 16 + qi)) * D_ + hq * DH_;
  f16x8 qf[4];
#pragma unroll
  for (int kd = 0; kd < 4; ++kd) {
    qf[kd] = *reinterpret_cast<const f16x8*>(Q + qbase + kd * 32 + grp * 8);
#pragma unroll
    for (int e = 0; e < 8; ++e) qf[kd][e] *= SCL2;
  }

  float m = -INFINITY, lsum = 0.f;
  f32x4 accO[8] = {};

  stage(0, 0);
  asm volatile("s_waitcnt vmcnt(0)" ::: "memory");
  __builtin_amdgcn_s_barrier();

  for (int t = 0; t < nt; ++t) {
    const int buf = t & 1;
    if (t + 1 < nt) stage(t + 1, buf ^ 1);   // overlaps this tile's compute

    const bool last = (t == nt - 1);
#pragma unroll
    for (int h = 0; h < 2; ++h) {
      const int kv0 = t * 64 + h * 32;
      if (kv0 > q_hi) break;                 // wave-uniform: fully-masked half
      const f16* sKh = &sK[buf][h * 32 * 128];
      const f16* sVb = &sV[buf][0];
      const int  gh  = h * 8;

      // QK^T (swapped): s{0,1}[jj] = S^T[kv0+half16*16+grp*4+jj][q=qi], log2 units
      f32x4 s0 = {}, s1 = {};
#pragma unroll
      for (int kd = 0; kd < 4; ++kd) {
        const int cx = ((kd * 4 + grp) ^ (qi & 7)) << 3;
        f16x8 k0 = *reinterpret_cast<const f16x8*>(sKh + qi * 128 + cx);
        f16x8 k1 = *reinterpret_cast<const f16x8*>(sKh + (16 + qi) * 128 + cx);
        s0 = __builtin_amdgcn_mfma_f32_16x16x32_f16(k0, qf[kd], s0, 0, 0, 0);
        s1 = __builtin_amdgcn_mfma_f32_16x16x32_f16(k1, qf[kd], s1, 0, 0, 0);
      }
      float p[8];
#pragma unroll
      for (int jj = 0; jj < 4; ++jj) { p[jj] = s0[jj]; p[4 + jj] = s1[jj]; }
      if (last) {                      // only the last tile can cross the diagonal
#pragma unroll
        for (int jj = 0; jj < 4; ++jj) {
          int kvp = kv0 + grp * 4 + jj;
          p[jj]     = (kvp > q_pos)      ? -INFINITY : p[jj];
          p[4 + jj] = (kvp + 16 > q_pos) ? -INFINITY : p[4 + jj];
        }
      }
      float tm = -INFINITY;
#pragma unroll
      for (int i = 0; i < 8; ++i) tm = fmaxf(tm, p[i]);
      if (!__all(tm <= m + 8.f)) {     // defer-max: rescale only on real growth (rare)
        float r = tm;
        r = fmaxf(r, __shfl_xor(r, 16));
        r = fmaxf(r, __shfl_xor(r, 32));
        float mn = fmaxf(m, r);
        float sc = exp2f(m - mn);
        m = mn;
        lsum *= sc;
#pragma unroll
        for (int dt = 0; dt < 8; ++dt)
#pragma unroll
          for (int jj = 0; jj < 4; ++jj) accO[dt][jj] *= sc;
      }
      float ps = 0.f;
#pragma unroll
      for (int i = 0; i < 8; ++i) {
        p[i] = exp2f(p[i] - m);
        ps += p[i];
      }
      lsum += ps;                      // per-lane partial, reduced at end

      f16x4 pf0 = { (f16)p[0], (f16)p[1], (f16)p[2], (f16)p[3] };
      f16x4 pf1 = { (f16)p[4], (f16)p[5], (f16)p[6], (f16)p[7] };
#pragma unroll
      for (int dt = 0; dt < 8; ++dt) {
        const int dl = dt * 16 + qi;
        const int c  = dl >> 1;
        const int g0 = gh + grp, g1 = gh + grp + 4;
        f16x4 v0 = *reinterpret_cast<const f16x4*>(
            sVb + g0 * 512 + ((c ^ g0) << 3) + (dl & 1) * 4);
        f16x4 v1 = *reinterpret_cast<const f16x4*>(
            sVb + g1 * 512 + ((c ^ g1) << 3) + (dl & 1) * 4);
        accO[dt] = __builtin_amdgcn_mfma_f32_16x16x16f16(v0, pf0, accO[dt], 0, 0, 0);
        accO[dt] = __builtin_amdgcn_mfma_f32_16x16x16f16(v1, pf1, accO[dt], 0, 0, 0);
      }
    }

    asm volatile("s_waitcnt vmcnt(0)" ::: "memory");  // next tile landed
    __builtin_amdgcn_s_barrier();
  }

  lsum += __shfl_xor(lsum, 16);
  lsum += __shfl_xor(lsum, 32);
  float inv_l = 1.f / lsum;
  const size_t obase = ((size_t)(b * S_ + qt * 16 + qi)) * D_ + hq * DH_;
#pragma unroll
  for (int dt = 0; dt < 8; ++dt) {
    f16x4 st;
#pragma unroll
    for (int jj = 0; jj < 4; ++jj) st[jj] = (f16)(accO[dt][jj] * inv_l);
    *reinterpret_cast<f16x4*>(&O[obase + dt * 16 + grp * 4]) = st;
  }
}

extern "C" void kernel_launch(void* const* d_in, const int* in_sizes, int n_in,
                              void* d_out, int out_size, void* d_ws, size_t ws_size,
                              hipStream_t stream) {
  const float* x  = (const float*)d_in[0];
  const float* Wq = (const float*)d_in[1];
  const float* bq = (const float*)d_in[2];
  const float* Wk = (const float*)d_in[3];
  const float* bk = (const float*)d_in[4];
  const float* Wv = (const float*)d_in[5];
  const float* bv = (const float*)d_in[6];
  const float* Wo = (const float*)d_in[7];
  const float* bo = (const float*)d_in[8];
  float* out = (float*)d_out;

  char* ws = (char*)d_ws;
  size_t off = 0;
  auto alloc = [&](size_t bytes) {
    char* p = ws + off;
    off += (bytes + 255) & ~(size_t)255;
    return p;
  };
  f16*   xh    = (f16*)alloc((size_t)B_ * S_ * D_ * 2);
  f16*   wqkv  = (f16*)alloc((size_t)NQKV_ * D_ * 2);
  f16*   woh   = (f16*)alloc((size_t)D_ * D_ * 2);
  f16*   qh    = (f16*)alloc((size_t)B_ * S_ * D_ * 2);
  f16*   kh    = (f16*)alloc((size_t)B_ * S_ * DKV_ * 2);
  f16*   v4h   = (f16*)alloc((size_t)B_ * S_ * DKV_ * 2);
  f16*   ah    = (f16*)alloc((size_t)B_ * S_ * D_ * 2);
  float* bqkv  = (float*)alloc((size_t)NQKV_ * 4);

  auto cast = [&](const float* in, f16* o, int n) {
    int n4 = n / 4;
    int grid = (n4 + 255) / 256;
    if (grid > 2048) grid = 2048;
    cast_kernel<<<dim3(grid), dim3(256), 0, stream>>>(in, o, n4);
  };
  cast(x,  xh, B_ * S_ * D_);
  cast(Wq, wqkv,                               D_ * D_);
  cast(Wk, wqkv + (size_t)D_ * D_,             DKV_ * D_);
  cast(Wv, wqkv + (size_t)(D_ + DKV_) * D_,    DKV_ * D_);
  cast(Wo, woh, D_ * D_);
  (void)hipMemcpyAsync(bqkv,             bq, D_ * 4,   hipMemcpyDeviceToDevice, stream);
  (void)hipMemcpyAsync(bqkv + D_,        bk, DKV_ * 4, hipMemcpyDeviceToDevice, stream);
  (void)hipMemcpyAsync(bqkv + D_ + DKV_, bv, DKV_ * 4, hipMemcpyDeviceToDevice, stream);

  const int M = B_ * S_;
  gemm_core<1><<<dim3((M / 128) * (NQKV_ / 128)), 256, 0, stream>>>(
      xh, wqkv, bqkv, qh, kh, v4h, nullptr, M, NQKV_, D_, NQKV_ / 128);

  attn_kernel<<<dim3(1024), 256, 0, stream>>>(qh, kh, v4h, ah);

  gemm_core<0><<<dim3((M / 128) * (D_ / 128)), 256, 0, stream>>>(
      ah, woh, bo, nullptr, nullptr, nullptr, out, M, D_, D_, D_ / 128);
}

// Round 12
// 221.862 us; speedup vs baseline: 1.2332x; 1.0753x over previous
//
#include <hip/hip_runtime.h>
#include <hip/hip_bf16.h>
#include <cmath>
#include <stdint.h>

#define B_ 2
#define S_ 2048
#define D_ 2048
#define H_ 16
#define HKV_ 2
#define DH_ 128
#define G_ 8
#define DKV_ 256   // HKV*DH
#define NQKV_ 2560 // D_ + 2*DKV

typedef _Float16 f16;
typedef _Float16 f16x8 __attribute__((ext_vector_type(8)));
typedef _Float16 f16x4 __attribute__((ext_vector_type(4)));
typedef float f32x4 __attribute__((ext_vector_type(4)));

__device__ __forceinline__ void gload_lds16(const void* g, void* lds) {
  __builtin_amdgcn_global_load_lds((const __attribute__((address_space(1))) void*)g,
                                   (__attribute__((address_space(3))) void*)lds,
                                   16, 0, 0);
}

__global__ void cast_kernel(const float* __restrict__ in, f16* __restrict__ out, int n4) {
  int i = blockIdx.x * blockDim.x + threadIdx.x;
  int stride = gridDim.x * blockDim.x;
  for (; i < n4; i += stride) {
    float4 v = reinterpret_cast<const float4*>(in)[i];
    f16x4 o = { (f16)v.x, (f16)v.y, (f16)v.z, (f16)v.w };
    reinterpret_cast<f16x4*>(out)[i] = o;
  }
}

// C[m][n] = sum_k A[m][k]*Bm[n][k] + bias[n].  1-D grid (nwg % 8 == 0), XCD-swizzled.
// Double-buffered LDS, stage(t+1) overlaps compute(t).
// LDS tiles are XOR-swizzled: 16B chunk c of row r stored at chunk position c^(r&7).
// Achieved by pre-swizzling the GLOBAL source column (LDS dest stays linear for
// global_load_lds) and XOR-ing the ds_read address (G21 both-sides pattern).
template<int EPI>
__global__ __launch_bounds__(256)
void gemm_core(const f16* __restrict__ A, const f16* __restrict__ Bm,
               const float* __restrict__ bias,
               f16* __restrict__ oQ, f16* __restrict__ oK, f16* __restrict__ oV,
               float* __restrict__ oF,
               int M, int N, int K, int nbx) {
  __shared__ __align__(16) f16 sA[2][128 * 64];
  __shared__ __align__(16) f16 sB[2][128 * 64];
  const int tid  = threadIdx.x;
  const int lane = tid & 63;
  const int w    = tid >> 6;
  const int wr   = w >> 1, wc = w & 1;
  const int r16  = lane & 15, grp = lane >> 4;
  const int nwg  = gridDim.x;
  const int cpx  = nwg >> 3;
  const int lg   = (blockIdx.x & 7) * cpx + (blockIdx.x >> 3);  // bijective XCD swizzle
  const int bm   = (lg / nbx) * 128;
  const int bn   = (lg % nbx) * 128;

  f32x4 acc[4][4] = {};

  auto stage = [&](int k0, int buf) {   // 8 gload_lds per thread; swizzled source
#pragma unroll
    for (int j = 0; j < 4; ++j) {
      int seg = j * 4 + w;                 // 8-row segment
      int rr  = seg * 8 + (lane >> 3);     // row in tile
      int cs  = lane & 7;                  // stored chunk index (linear in LDS)
      int csr = (cs ^ (rr & 7)) * 8;       // source column (pre-swizzled)
      gload_lds16(A  + (size_t)(bm + rr) * K + k0 + csr, &sA[buf][seg * 512]);
      gload_lds16(Bm + (size_t)(bn + rr) * K + k0 + csr, &sB[buf][seg * 512]);
    }
  };

  stage(0, 0);
  asm volatile("s_waitcnt vmcnt(0)" ::: "memory");
  __builtin_amdgcn_s_barrier();

  const int nk = K >> 6;
  for (int t = 0; t < nk; ++t) {
    const int buf = t & 1;
    if (t + 1 < nk) stage((t + 1) << 6, buf ^ 1);

#pragma unroll
    for (int kk = 0; kk < 64; kk += 32) {
      f16x8 af[4], bf[4];
      const int cb = (kk >> 3) + grp;      // logical chunk of this fragment
      const int cx = (cb ^ (r16 & 7)) << 3;  // swizzled f16 offset within row
#pragma unroll
      for (int m = 0; m < 4; ++m)
        af[m] = *reinterpret_cast<const f16x8*>(&sA[buf][(wr * 64 + m * 16 + r16) * 64 + cx]);
#pragma unroll
      for (int n = 0; n < 4; ++n)
        bf[n] = *reinterpret_cast<const f16x8*>(&sB[buf][(wc * 64 + n * 16 + r16) * 64 + cx]);
#pragma unroll
      for (int m = 0; m < 4; ++m)
#pragma unroll
        for (int n = 0; n < 4; ++n)
          acc[m][n] = __builtin_amdgcn_mfma_f32_16x16x32_f16(af[m], bf[n], acc[m][n], 0, 0, 0);
    }

    asm volatile("s_waitcnt vmcnt(0)" ::: "memory");  // next tile landed (overlapped compute)
    __builtin_amdgcn_s_barrier();
  }

#pragma unroll
  for (int n = 0; n < 4; ++n) {
    int col = bn + wc * 64 + n * 16 + r16;
    float bv = bias ? bias[col] : 0.f;
#pragma unroll
    for (int m = 0; m < 4; ++m) {
      int row0 = bm + wr * 64 + m * 16 + grp * 4;   // 4-aligned
      if constexpr (EPI == 0) {
#pragma unroll
        for (int j = 0; j < 4; ++j)
          oF[(size_t)(row0 + j) * N + col] = acc[m][n][j] + bv;
      } else {
        if (bn < 2048) {
#pragma unroll
          for (int j = 0; j < 4; ++j)
            oQ[(size_t)(row0 + j) * 2048 + col] = (f16)(acc[m][n][j] + bv);
        } else if (bn < 2304) {
#pragma unroll
          for (int j = 0; j < 4; ++j)
            oK[(size_t)(row0 + j) * 256 + (col - 2048)] = (f16)(acc[m][n][j] + bv);
        } else {
          f16x4 st;
#pragma unroll
          for (int j = 0; j < 4; ++j) st[j] = (f16)(acc[m][n][j] + bv);
          *reinterpret_cast<f16x4*>(&oV[(size_t)(row0 >> 2) * 1024 + (col - 2304) * 4]) = st;
        }
      }
    }
  }
}

// Flash attention, causal, GQA.  1024 blocks, one task each:
//   (b,kvh,hh) = bid&7, qt = 127 - (bid>>3)  (longest-first dynamic-LPT dispatch).
// Block = 4 waves = 4 q-heads sharing one kv-head's K/V LDS tiles.
// KVBLK=64: 2-buffer LDS (64KB total), depth-1 prefetch, two 32-kv halves per tile.
__global__ __launch_bounds__(256)
void attn_kernel(const f16* __restrict__ Q, const f16* __restrict__ K,
                 const f16* __restrict__ V4, f16* __restrict__ O) {
  __shared__ __align__(16) f16 sK[2][8192];   // [buf][64 rows x 128], XOR-swizzled 16B chunks
  __shared__ __align__(16) f16 sV[2][8192];   // [buf][16 grp x 512],  XOR-swizzled 16B chunks

  const int tid  = threadIdx.x;
  const int lane = tid & 63;
  const int w    = tid >> 6;
  const int qi   = lane & 15, grp = lane >> 4;
  const int bid  = blockIdx.x;
  const int hh   = bid & 1;
  const int kvh  = (bid >> 1) & 1;
  const int b    = (bid >> 2) & 1;
  const int qt   = 127 - (bid >> 3);   // longest tasks dispatch first
  const int hq   = kvh * 8 + hh * 4 + w;
  const f16 SCL2 = (f16)(0.08838834764831845f * 1.44269504088896f);  // 1/sqrt(128)*log2(e)

  const f16* Kb = K  + (size_t)b * S_ * DKV_ + kvh * DH_;
  const f16* Vb = V4 + (size_t)b * S_ * DKV_ + kvh * 512;

  auto stage = [&](int t64, int buf) {   // exactly 8 vm loads per thread (64 kv rows)
#pragma unroll
    for (int p4 = 0; p4 < 4; ++p4) {
      int ci = p4 * 256 + tid;
      int r = ci >> 4, cs = ci & 15;
      gload_lds16(Kb + (size_t)(t64 * 64 + r) * DKV_ + ((cs ^ (r & 7)) * 8),
                  (char*)&sK[buf][0] + p4 * 4096 + w * 1024);
      int g = ci >> 6, cc = ci & 63;
      gload_lds16(Vb + (size_t)(t64 * 16 + g) * 1024 + ((cc ^ g) * 8),
                  (char*)&sV[buf][0] + p4 * 4096 + w * 1024);
    }
  };

  const int nt    = (qt >> 2) + 1;     // 64-kv tiles
  const int q_pos = qt * 16 + qi;
  const int q_hi  = qt * 16 + 15;

  const size_t qbase = ((size_t)(b * S_ + qt * 16 + qi)) * D_ + hq * DH_;
  f16x8 qf[4];
#pragma unroll
  for (int kd = 0; kd < 4; ++kd) {
    qf[kd] = *reinterpret_cast<const f16x8*>(Q + qbase + kd * 32 + grp * 8);
#pragma unroll
    for (int e = 0; e < 8; ++e) qf[kd][e] *= SCL2;
  }

  float m = -INFINITY, lsum = 0.f;
  f32x4 accO[8] = {};

  stage(0, 0);
  asm volatile("s_waitcnt vmcnt(0)" ::: "memory");
  __builtin_amdgcn_s_barrier();

  for (int t = 0; t < nt; ++t) {
    const int buf = t & 1;
    if (t + 1 < nt) stage(t + 1, buf ^ 1);   // overlaps this tile's compute

    const bool last = (t == nt - 1);
#pragma unroll
    for (int h = 0; h < 2; ++h) {
      const int kv0 = t * 64 + h * 32;
      if (kv0 > q_hi) break;                 // wave-uniform: fully-masked half
      const f16* sKh = &sK[buf][h * 32 * 128];
      const f16* sVb = &sV[buf][0];
      const int  gh  = h * 8;

      // QK^T (swapped): s{0,1}[jj] = S^T[kv0+half16*16+grp*4+jj][q=qi], log2 units
      f32x4 s0 = {}, s1 = {};
#pragma unroll
      for (int kd = 0; kd < 4; ++kd) {
        const int cx = ((kd * 4 + grp) ^ (qi & 7)) << 3;
        f16x8 k0 = *reinterpret_cast<const f16x8*>(sKh + qi * 128 + cx);
        f16x8 k1 = *reinterpret_cast<const f16x8*>(sKh + (16 + qi) * 128 + cx);
        s0 = __builtin_amdgcn_mfma_f32_16x16x32_f16(k0, qf[kd], s0, 0, 0, 0);
        s1 = __builtin_amdgcn_mfma_f32_16x16x32_f16(k1, qf[kd], s1, 0, 0, 0);
      }
      float p[8];
#pragma unroll
      for (int jj = 0; jj < 4; ++jj) { p[jj] = s0[jj]; p[4 + jj] = s1[jj]; }
      if (last) {                      // only the last tile can cross the diagonal
#pragma unroll
        for (int jj = 0; jj < 4; ++jj) {
          int kvp = kv0 + grp * 4 + jj;
          p[jj]     = (kvp > q_pos)      ? -INFINITY : p[jj];
          p[4 + jj] = (kvp + 16 > q_pos) ? -INFINITY : p[4 + jj];
        }
      }
      float tm = -INFINITY;
#pragma unroll
      for (int i = 0; i < 8; ++i) tm = fmaxf(tm, p[i]);
      if (!__all(tm <= m + 8.f)) {     // defer-max: rescale only on real growth (rare)
        float r = tm;
        r = fmaxf(r, __shfl_xor(r, 16));
        r = fmaxf(r, __shfl_xor(r, 32));
        float mn = fmaxf(m, r);
        float sc = exp2f(m - mn);
        m = mn;
        lsum *= sc;
#pragma unroll
        for (int dt = 0; dt < 8; ++dt)
#pragma unroll
          for (int jj = 0; jj < 4; ++jj) accO[dt][jj] *= sc;
      }
      float ps = 0.f;
#pragma unroll
      for (int i = 0; i < 8; ++i) {
        p[i] = exp2f(p[i] - m);
        ps += p[i];
      }
      lsum += ps;                      // per-lane partial, reduced at end

      f16x4 pf0 = { (f16)p[0], (f16)p[1], (f16)p[2], (f16)p[3] };
      f16x4 pf1 = { (f16)p[4], (f16)p[5], (f16)p[6], (f16)p[7] };
#pragma unroll
      for (int dt = 0; dt < 8; ++dt) {
        const int dl = dt * 16 + qi;
        const int c  = dl >> 1;
        const int g0 = gh + grp, g1 = gh + grp + 4;
        f16x4 v0 = *reinterpret_cast<const f16x4*>(
            sVb + g0 * 512 + ((c ^ g0) << 3) + (dl & 1) * 4);
        f16x4 v1 = *reinterpret_cast<const f16x4*>(
            sVb + g1 * 512 + ((c ^ g1) << 3) + (dl & 1) * 4);
        accO[dt] = __builtin_amdgcn_mfma_f32_16x16x16f16(v0, pf0, accO[dt], 0, 0, 0);
        accO[dt] = __builtin_amdgcn_mfma_f32_16x16x16f16(v1, pf1, accO[dt], 0, 0, 0);
      }
    }

    asm volatile("s_waitcnt vmcnt(0)" ::: "memory");  // next tile landed
    __builtin_amdgcn_s_barrier();
  }

  lsum += __shfl_xor(lsum, 16);
  lsum += __shfl_xor(lsum, 32);
  float inv_l = 1.f / lsum;
  const size_t obase = ((size_t)(b * S_ + qt * 16 + qi)) * D_ + hq * DH_;
#pragma unroll
  for (int dt = 0; dt < 8; ++dt) {
    f16x4 st;
#pragma unroll
    for (int jj = 0; jj < 4; ++jj) st[jj] = (f16)(accO[dt][jj] * inv_l);
    *reinterpret_cast<f16x4*>(&O[obase + dt * 16 + grp * 4]) = st;
  }
}

extern "C" void kernel_launch(void* const* d_in, const int* in_sizes, int n_in,
                              void* d_out, int out_size, void* d_ws, size_t ws_size,
                              hipStream_t stream) {
  const float* x  = (const float*)d_in[0];
  const float* Wq = (const float*)d_in[1];
  const float* bq = (const float*)d_in[2];
  const float* Wk = (const float*)d_in[3];
  const float* bk = (const float*)d_in[4];
  const float* Wv = (const float*)d_in[5];
  const float* bv = (const float*)d_in[6];
  const float* Wo = (const float*)d_in[7];
  const float* bo = (const float*)d_in[8];
  float* out = (float*)d_out;

  char* ws = (char*)d_ws;
  size_t off = 0;
  auto alloc = [&](size_t bytes) {
    char* p = ws + off;
    off += (bytes + 255) & ~(size_t)255;
    return p;
  };
  f16*   xh    = (f16*)alloc((size_t)B_ * S_ * D_ * 2);
  f16*   wqkv  = (f16*)alloc((size_t)NQKV_ * D_ * 2);
  f16*   woh   = (f16*)alloc((size_t)D_ * D_ * 2);
  f16*   qh    = (f16*)alloc((size_t)B_ * S_ * D_ * 2);
  f16*   kh    = (f16*)alloc((size_t)B_ * S_ * DKV_ * 2);
  f16*   v4h   = (f16*)alloc((size_t)B_ * S_ * DKV_ * 2);
  f16*   ah    = (f16*)alloc((size_t)B_ * S_ * D_ * 2);
  float* bqkv  = (float*)alloc((size_t)NQKV_ * 4);

  auto cast = [&](const float* in, f16* o, int n) {
    int n4 = n / 4;
    int grid = (n4 + 255) / 256;
    if (grid > 2048) grid = 2048;
    cast_kernel<<<dim3(grid), dim3(256), 0, stream>>>(in, o, n4);
  };
  cast(x,  xh, B_ * S_ * D_);
  cast(Wq, wqkv,                               D_ * D_);
  cast(Wk, wqkv + (size_t)D_ * D_,             DKV_ * D_);
  cast(Wv, wqkv + (size_t)(D_ + DKV_) * D_,    DKV_ * D_);
  cast(Wo, woh, D_ * D_);
  (void)hipMemcpyAsync(bqkv,             bq, D_ * 4,   hipMemcpyDeviceToDevice, stream);
  (void)hipMemcpyAsync(bqkv + D_,        bk, DKV_ * 4, hipMemcpyDeviceToDevice, stream);
  (void)hipMemcpyAsync(bqkv + D_ + DKV_, bv, DKV_ * 4, hipMemcpyDeviceToDevice, stream);

  const int M = B_ * S_;
  gemm_core<1><<<dim3((M / 128) * (NQKV_ / 128)), 256, 0, stream>>>(
      xh, wqkv, bqkv, qh, kh, v4h, nullptr, M, NQKV_, D_, NQKV_ / 128);

  attn_kernel<<<dim3(1024), 256, 0, stream>>>(qh, kh, v4h, ah);

  gemm_core<0><<<dim3((M / 128) * (D_ / 128)), 256, 0, stream>>>(
      ah, woh, bo, nullptr, nullptr, nullptr, out, M, D_, D_, D_ / 128);
}

// Round 13
// 213.190 us; speedup vs baseline: 1.2833x; 1.0407x over previous
//
#include <hip/hip_runtime.h>
#include <hip/hip_bf16.h>
#include <cmath>
#include <stdint.h>

#define B_ 2
#define S_ 2048
#define D_ 2048
#define H_ 16
#define HKV_ 2
#define DH_ 128
#define G_ 8
#define DKV_ 256   // HKV*DH
#define NQKV_ 2560 // D_ + 2*DKV

typedef _Float16 f16;
typedef _Float16 f16x8 __attribute__((ext_vector_type(8)));
typedef _Float16 f16x4 __attribute__((ext_vector_type(4)));
typedef float f32x4 __attribute__((ext_vector_type(4)));

__device__ __forceinline__ void gload_lds16(const void* g, void* lds) {
  __builtin_amdgcn_global_load_lds((const __attribute__((address_space(1))) void*)g,
                                   (__attribute__((address_space(3))) void*)lds,
                                   16, 0, 0);
}

// raw v_exp_f32 (2^x): skips the compiler's denormal-range fixup.  Inputs here
// are <= 8; -inf -> 0 and sub-denormal flush are exactly what softmax wants.
__device__ __forceinline__ float fexp2(float x) {
  float r;
  asm("v_exp_f32 %0, %1" : "=v"(r) : "v"(x));
  return r;
}

__global__ void cast_kernel(const float* __restrict__ in, f16* __restrict__ out, int n4) {
  int i = blockIdx.x * blockDim.x + threadIdx.x;
  int stride = gridDim.x * blockDim.x;
  for (; i < n4; i += stride) {
    float4 v = reinterpret_cast<const float4*>(in)[i];
    f16x4 o = { (f16)v.x, (f16)v.y, (f16)v.z, (f16)v.w };
    reinterpret_cast<f16x4*>(out)[i] = o;
  }
}

// C[m][n] = sum_k A[m][k]*Bm[n][k] + bias[n].  1-D grid (nwg % 8 == 0), XCD-swizzled.
// Double-buffered LDS, stage(t+1) overlaps compute(t).
// LDS tiles are XOR-swizzled: 16B chunk c of row r stored at chunk position c^(r&7).
template<int EPI>
__global__ __launch_bounds__(256)
void gemm_core(const f16* __restrict__ A, const f16* __restrict__ Bm,
               const float* __restrict__ bias,
               f16* __restrict__ oQ, f16* __restrict__ oK, f16* __restrict__ oV,
               float* __restrict__ oF,
               int M, int N, int K, int nbx) {
  __shared__ __align__(16) f16 sA[2][128 * 64];
  __shared__ __align__(16) f16 sB[2][128 * 64];
  const int tid  = threadIdx.x;
  const int lane = tid & 63;
  const int w    = tid >> 6;
  const int wr   = w >> 1, wc = w & 1;
  const int r16  = lane & 15, grp = lane >> 4;
  const int nwg  = gridDim.x;
  const int cpx  = nwg >> 3;
  const int lg   = (blockIdx.x & 7) * cpx + (blockIdx.x >> 3);  // bijective XCD swizzle
  const int bm   = (lg / nbx) * 128;
  const int bn   = (lg % nbx) * 128;

  f32x4 acc[4][4] = {};

  auto stage = [&](int k0, int buf) {   // 8 gload_lds per thread; swizzled source
#pragma unroll
    for (int j = 0; j < 4; ++j) {
      int seg = j * 4 + w;                 // 8-row segment
      int rr  = seg * 8 + (lane >> 3);     // row in tile
      int cs  = lane & 7;                  // stored chunk index (linear in LDS)
      int csr = (cs ^ (rr & 7)) * 8;       // source column (pre-swizzled)
      gload_lds16(A  + (size_t)(bm + rr) * K + k0 + csr, &sA[buf][seg * 512]);
      gload_lds16(Bm + (size_t)(bn + rr) * K + k0 + csr, &sB[buf][seg * 512]);
    }
  };

  stage(0, 0);
  asm volatile("s_waitcnt vmcnt(0)" ::: "memory");
  __builtin_amdgcn_s_barrier();

  const int nk = K >> 6;
  for (int t = 0; t < nk; ++t) {
    const int buf = t & 1;
    if (t + 1 < nk) stage((t + 1) << 6, buf ^ 1);

#pragma unroll
    for (int kk = 0; kk < 64; kk += 32) {
      f16x8 af[4], bf[4];
      const int cb = (kk >> 3) + grp;        // logical chunk of this fragment
      const int cx = (cb ^ (r16 & 7)) << 3;  // swizzled f16 offset within row
#pragma unroll
      for (int m = 0; m < 4; ++m)
        af[m] = *reinterpret_cast<const f16x8*>(&sA[buf][(wr * 64 + m * 16 + r16) * 64 + cx]);
#pragma unroll
      for (int n = 0; n < 4; ++n)
        bf[n] = *reinterpret_cast<const f16x8*>(&sB[buf][(wc * 64 + n * 16 + r16) * 64 + cx]);
#pragma unroll
      for (int m = 0; m < 4; ++m)
#pragma unroll
        for (int n = 0; n < 4; ++n)
          acc[m][n] = __builtin_amdgcn_mfma_f32_16x16x32_f16(af[m], bf[n], acc[m][n], 0, 0, 0);
    }

    asm volatile("s_waitcnt vmcnt(0)" ::: "memory");  // next tile landed (overlapped compute)
    __builtin_amdgcn_s_barrier();
  }

#pragma unroll
  for (int n = 0; n < 4; ++n) {
    int col = bn + wc * 64 + n * 16 + r16;
    float bv = bias ? bias[col] : 0.f;
#pragma unroll
    for (int m = 0; m < 4; ++m) {
      int row0 = bm + wr * 64 + m * 16 + grp * 4;   // 4-aligned
      if constexpr (EPI == 0) {
#pragma unroll
        for (int j = 0; j < 4; ++j)
          oF[(size_t)(row0 + j) * N + col] = acc[m][n][j] + bv;
      } else {
        if (bn < 2048) {
#pragma unroll
          for (int j = 0; j < 4; ++j)
            oQ[(size_t)(row0 + j) * 2048 + col] = (f16)(acc[m][n][j] + bv);
        } else if (bn < 2304) {
#pragma unroll
          for (int j = 0; j < 4; ++j)
            oK[(size_t)(row0 + j) * 256 + (col - 2048)] = (f16)(acc[m][n][j] + bv);
        } else {
          f16x4 st;
#pragma unroll
          for (int j = 0; j < 4; ++j) st[j] = (f16)(acc[m][n][j] + bv);
          *reinterpret_cast<f16x4*>(&oV[(size_t)(row0 >> 2) * 1024 + (col - 2304) * 4]) = st;
        }
      }
    }
  }
}

// Flash attention, causal, GQA.  1024 blocks, one task each:
//   (b,kvh,hh) = bid&7, qt = 127 - (bid>>3)  (longest-first dynamic-LPT dispatch).
// Block = 4 waves = 4 q-heads sharing one kv-head's K/V LDS tiles.
// KVBLK=64: 2-buffer LDS (64KB total), depth-1 prefetch, two 32-kv halves per tile.
// PV addresses decomposed: base + dtp*64 immediates (dt = dtp^h, h unroll-const).
__global__ __launch_bounds__(256)
void attn_kernel(const f16* __restrict__ Q, const f16* __restrict__ K,
                 const f16* __restrict__ V4, f16* __restrict__ O) {
  __shared__ __align__(16) f16 sK[2][8192];   // [buf][64 rows x 128], XOR-swizzled 16B chunks
  __shared__ __align__(16) f16 sV[2][8192];   // [buf][16 grp x 512],  XOR-swizzled 16B chunks

  const int tid  = threadIdx.x;
  const int lane = tid & 63;
  const int w    = tid >> 6;
  const int qi   = lane & 15, grp = lane >> 4;
  const int bid  = blockIdx.x;
  const int hh   = bid & 1;
  const int kvh  = (bid >> 1) & 1;
  const int b    = (bid >> 2) & 1;
  const int qt   = 127 - (bid >> 3);   // longest tasks dispatch first
  const int hq   = kvh * 8 + hh * 4 + w;
  const f16 SCL2 = (f16)(0.08838834764831845f * 1.44269504088896f);  // 1/sqrt(128)*log2(e)

  const f16* Kb = K  + (size_t)b * S_ * DKV_ + kvh * DH_;
  const f16* Vb = V4 + (size_t)b * S_ * DKV_ + kvh * 512;

  auto stage = [&](int t64, int buf) {   // exactly 8 vm loads per thread (64 kv rows)
#pragma unroll
    for (int p4 = 0; p4 < 4; ++p4) {
      int ci = p4 * 256 + tid;
      int r = ci >> 4, cs = ci & 15;
      gload_lds16(Kb + (size_t)(t64 * 64 + r) * DKV_ + ((cs ^ (r & 7)) * 8),
                  (char*)&sK[buf][0] + p4 * 4096 + w * 1024);
      int g = ci >> 6, cc = ci & 63;
      gload_lds16(Vb + (size_t)(t64 * 16 + g) * 1024 + ((cc ^ g) * 8),
                  (char*)&sV[buf][0] + p4 * 4096 + w * 1024);
    }
  };

  const int nt    = (qt >> 2) + 1;     // 64-kv tiles
  const int q_pos = qt * 16 + qi;
  const int q_hi  = qt * 16 + 15;

  const size_t qbase = ((size_t)(b * S_ + qt * 16 + qi)) * D_ + hq * DH_;
  f16x8 qf[4];
#pragma unroll
  for (int kd = 0; kd < 4; ++kd) {
    qf[kd] = *reinterpret_cast<const f16x8*>(Q + qbase + kd * 32 + grp * 8);
#pragma unroll
    for (int e = 0; e < 8; ++e) qf[kd][e] *= SCL2;
  }

  // PV address decomposition (t/h-invariant parts)
  const int q2    = qi >> 1;
  const int voff0 = ((q2 ^ grp) << 3) + (qi & 1) * 4;
  const int voff1 = ((q2 ^ (grp + 4)) << 3) + (qi & 1) * 4;

  float m = -INFINITY, lsum = 0.f;
  f32x4 accO[8] = {};

  stage(0, 0);
  asm volatile("s_waitcnt vmcnt(0)" ::: "memory");
  __builtin_amdgcn_s_barrier();

  for (int t = 0; t < nt; ++t) {
    const int buf = t & 1;
    if (t + 1 < nt) stage(t + 1, buf ^ 1);   // overlaps this tile's compute

    const bool last = (t == nt - 1);
    const f16* sVb = &sV[buf][0];
#pragma unroll
    for (int h = 0; h < 2; ++h) {
      const int kv0 = t * 64 + h * 32;
      if (kv0 > q_hi) break;                 // wave-uniform: fully-masked half
      const f16* sKh = &sK[buf][h * 32 * 128];

      // QK^T (swapped): s{0,1}[jj] = S^T[kv0+half16*16+grp*4+jj][q=qi], log2 units
      f32x4 s0 = {}, s1 = {};
#pragma unroll
      for (int kd = 0; kd < 4; ++kd) {
        const int cx = ((kd * 4 + grp) ^ (qi & 7)) << 3;
        f16x8 k0 = *reinterpret_cast<const f16x8*>(sKh + qi * 128 + cx);
        f16x8 k1 = *reinterpret_cast<const f16x8*>(sKh + (16 + qi) * 128 + cx);
        s0 = __builtin_amdgcn_mfma_f32_16x16x32_f16(k0, qf[kd], s0, 0, 0, 0);
        s1 = __builtin_amdgcn_mfma_f32_16x16x32_f16(k1, qf[kd], s1, 0, 0, 0);
      }
      float p[8];
#pragma unroll
      for (int jj = 0; jj < 4; ++jj) { p[jj] = s0[jj]; p[4 + jj] = s1[jj]; }
      if (last) {                      // only the last tile can cross the diagonal
#pragma unroll
        for (int jj = 0; jj < 4; ++jj) {
          int kvp = kv0 + grp * 4 + jj;
          p[jj]     = (kvp > q_pos)      ? -INFINITY : p[jj];
          p[4 + jj] = (kvp + 16 > q_pos) ? -INFINITY : p[4 + jj];
        }
      }
      float tm = -INFINITY;
#pragma unroll
      for (int i = 0; i < 8; ++i) tm = fmaxf(tm, p[i]);
      if (!__all(tm <= m + 8.f)) {     // defer-max: rescale only on real growth (rare)
        float r = tm;
        r = fmaxf(r, __shfl_xor(r, 16));
        r = fmaxf(r, __shfl_xor(r, 32));
        float mn = fmaxf(m, r);
        float sc = fexp2(m - mn);
        m = mn;
        lsum *= sc;
#pragma unroll
        for (int dt = 0; dt < 8; ++dt)
#pragma unroll
          for (int jj = 0; jj < 4; ++jj) accO[dt][jj] *= sc;
      }
      float ps = 0.f;
#pragma unroll
      for (int i = 0; i < 8; ++i) {
        p[i] = fexp2(p[i] - m);
        ps += p[i];
      }
      lsum += ps;                      // per-lane partial, reduced at end

      f16x4 pf0 = { (f16)p[0], (f16)p[1], (f16)p[2], (f16)p[3] };
      f16x4 pf1 = { (f16)p[4], (f16)p[5], (f16)p[6], (f16)p[7] };
      // PV: hoisted bases + compile-time offsets; acc index dt = dtp^h
      const f16* vb0 = sVb + (h * 8 + grp) * 512 + voff0;
      const f16* vb1 = sVb + (h * 8 + grp + 4) * 512 + voff1;
#pragma unroll
      for (int dtp = 0; dtp < 8; ++dtp) {
        const int dt = dtp ^ h;
        f16x4 v0 = *reinterpret_cast<const f16x4*>(vb0 + dtp * 64);
        f16x4 v1 = *reinterpret_cast<const f16x4*>(vb1 + dtp * 64);
        accO[dt] = __builtin_amdgcn_mfma_f32_16x16x16f16(v0, pf0, accO[dt], 0, 0, 0);
        accO[dt] = __builtin_amdgcn_mfma_f32_16x16x16f16(v1, pf1, accO[dt], 0, 0, 0);
      }
    }

    asm volatile("s_waitcnt vmcnt(0)" ::: "memory");  // next tile landed
    __builtin_amdgcn_s_barrier();
  }

  lsum += __shfl_xor(lsum, 16);
  lsum += __shfl_xor(lsum, 32);
  float inv_l = 1.f / lsum;
  const size_t obase = ((size_t)(b * S_ + qt * 16 + qi)) * D_ + hq * DH_;
#pragma unroll
  for (int dt = 0; dt < 8; ++dt) {
    f16x4 st;
#pragma unroll
    for (int jj = 0; jj < 4; ++jj) st[jj] = (f16)(accO[dt][jj] * inv_l);
    *reinterpret_cast<f16x4*>(&O[obase + dt * 16 + grp * 4]) = st;
  }
}

extern "C" void kernel_launch(void* const* d_in, const int* in_sizes, int n_in,
                              void* d_out, int out_size, void* d_ws, size_t ws_size,
                              hipStream_t stream) {
  const float* x  = (const float*)d_in[0];
  const float* Wq = (const float*)d_in[1];
  const float* bq = (const float*)d_in[2];
  const float* Wk = (const float*)d_in[3];
  const float* bk = (const float*)d_in[4];
  const float* Wv = (const float*)d_in[5];
  const float* bv = (const float*)d_in[6];
  const float* Wo = (const float*)d_in[7];
  const float* bo = (const float*)d_in[8];
  float* out = (float*)d_out;

  char* ws = (char*)d_ws;
  size_t off = 0;
  auto alloc = [&](size_t bytes) {
    char* p = ws + off;
    off += (bytes + 255) & ~(size_t)255;
    return p;
  };
  f16*   xh    = (f16*)alloc((size_t)B_ * S_ * D_ * 2);
  f16*   wqkv  = (f16*)alloc((size_t)NQKV_ * D_ * 2);
  f16*   woh   = (f16*)alloc((size_t)D_ * D_ * 2);
  f16*   qh    = (f16*)alloc((size_t)B_ * S_ * D_ * 2);
  f16*   kh    = (f16*)alloc((size_t)B_ * S_ * DKV_ * 2);
  f16*   v4h   = (f16*)alloc((size_t)B_ * S_ * DKV_ * 2);
  f16*   ah    = (f16*)alloc((size_t)B_ * S_ * D_ * 2);
  float* bqkv  = (float*)alloc((size_t)NQKV_ * 4);

  auto cast = [&](const float* in, f16* o, int n) {
    int n4 = n / 4;
    int grid = (n4 + 255) / 256;
    if (grid > 2048) grid = 2048;
    cast_kernel<<<dim3(grid), dim3(256), 0, stream>>>(in, o, n4);
  };
  cast(x,  xh, B_ * S_ * D_);
  cast(Wq, wqkv,                               D_ * D_);
  cast(Wk, wqkv + (size_t)D_ * D_,             DKV_ * D_);
  cast(Wv, wqkv + (size_t)(D_ + DKV_) * D_,    DKV_ * D_);
  cast(Wo, woh, D_ * D_);
  (void)hipMemcpyAsync(bqkv,             bq, D_ * 4,   hipMemcpyDeviceToDevice, stream);
  (void)hipMemcpyAsync(bqkv + D_,        bk, DKV_ * 4, hipMemcpyDeviceToDevice, stream);
  (void)hipMemcpyAsync(bqkv + D_ + DKV_, bv, DKV_ * 4, hipMemcpyDeviceToDevice, stream);

  const int M = B_ * S_;
  gemm_core<1><<<dim3((M / 128) * (NQKV_ / 128)), 256, 0, stream>>>(
      xh, wqkv, bqkv, qh, kh, v4h, nullptr, M, NQKV_, D_, NQKV_ / 128);

  attn_kernel<<<dim3(1024), 256, 0, stream>>>(qh, kh, v4h, ah);

  gemm_core<0><<<dim3((M / 128) * (D_ / 128)), 256, 0, stream>>>(
      ah, woh, bo, nullptr, nullptr, nullptr, out, M, D_, D_, D_ / 128);
}